// Round 8
// baseline (222.220 us; speedup 1.0000x reference)
//
#include <hip/hip_runtime.h>
#include <stdint.h>

typedef _Float16 half_t;
typedef __attribute__((ext_vector_type(8))) _Float16 half8;
typedef __attribute__((ext_vector_type(4))) _Float16 half4;
typedef __attribute__((ext_vector_type(4))) float floatx4;

#define SEQ 2048
#define NH 16
#define HD 64

#define MFMA16(a, b, c) __builtin_amdgcn_mfma_f32_16x16x16f16(a, b, c, 0, 0, 0)
#define MFMA32K(a, b, c) __builtin_amdgcn_mfma_f32_16x16x32_f16(a, b, c, 0, 0, 0)

// SCALE * log2(e): scores exit QK in log2 domain -> raw v_exp_f32
#define QSCALE 0.1803368801111306f

// ---------------- prep: casts + weight transposes + mask tables -------------
__global__ __launch_bounds__(256) void prep(
    const float* __restrict__ query, const float* __restrict__ key_value,
    const float* __restrict__ Wq, const float* __restrict__ Wkv,
    const float* __restrict__ Wo, half_t* __restrict__ xq,
    half_t* __restrict__ xkv, half_t* __restrict__ wqT,
    half_t* __restrict__ wkvT, half_t* __restrict__ woT,
    uint8_t* __restrict__ tok, uint8_t* __restrict__ tok16,
    uint64_t* __restrict__ maskw) {
  int bx = blockIdx.x, tid = threadIdx.x;
  if (bx < 2048) {  // fp32 -> f16 casts, 4096 elements per block
    const float* s; half_t* d; int base;
    if (bx < 1024) { s = query; d = xq; base = bx * 4096; }
    else { s = key_value; d = xkv; base = (bx - 1024) * 4096; }
#pragma unroll
    for (int u = 0; u < 4; ++u) {
      int i = base + u * 1024 + tid * 4;
      floatx4 v = *(const floatx4*)(s + i);
      half4 h;
      h[0] = (half_t)v[0]; h[1] = (half_t)v[1];
      h[2] = (half_t)v[2]; h[3] = (half_t)v[3];
      *(half4*)(d + i) = h;
    }
    return;
  }
  if (bx < 4096) {  // weight transpose+cast, 2 tiles per block
    __shared__ float tile[32][33];
    int tx = tid & 31, ty = tid >> 5;
    const int K = 1024;
#pragma unroll
    for (int u = 0; u < 2; ++u) {
      int t = (bx - 2048) * 2 + u;
      const float* W; half_t* Wt; int N, nt, kt;
      if (t < 1024) { W = Wq; Wt = wqT; N = 1024; nt = t & 31; kt = t >> 5; }
      else if (t < 3072) { int t2 = t - 1024; W = Wkv; Wt = wkvT; N = 2048; nt = t2 & 63; kt = t2 >> 6; }
      else { int t2 = t - 3072; W = Wo; Wt = woT; N = 1024; nt = t2 & 31; kt = t2 >> 5; }
      int n0 = nt * 32, k0 = kt * 32;
#pragma unroll
      for (int i = 0; i < 4; ++i)
        tile[ty + i * 8][tx] = W[(size_t)(k0 + ty + i * 8) * N + n0 + tx];
      __syncthreads();
#pragma unroll
      for (int i = 0; i < 4; ++i)
        Wt[(size_t)(n0 + ty + i * 8) * K + k0 + tx] = (half_t)tile[tx][ty + i * 8];
      __syncthreads();
    }
    return;
  }
  // mask tables
  __shared__ uint8_t slut[2048];
  int ib = bx - 4096;
  for (int d = tid; d < 2048; d += 256) {
    int x = d;
    bool ok = true;
    for (int it = 0; it < 7; ++it) { ok &= ((x % 3) != 1); x /= 3; }
    ok &= (x == 0);
    slut[d] = (ok || d <= 64) ? 1 : 0;
  }
  __syncthreads();
  if (ib == 0) {
    if (tid < 64) {  // 64-gran tile activity
      int delta = tid - 32;
      int lo = delta * 64 - 63, hi = delta * 64 + 63;
      uint8_t any = 0;
      for (int x = lo; x <= hi; ++x) {
        int a = x < 0 ? -x : x;
        if (a < 2048) any |= slut[a];
      }
      tok[tid] = any;
    }
    {  // 16-gran subtile activity
      int d16 = tid - 128;
      int ctr = d16 * 16;
      uint8_t any = 0;
      for (int x = ctr - 15; x <= ctr + 15; ++x) {
        int a = x < 0 ? -x : x;
        if (a < 2048) any |= slut[a];
      }
      tok16[tid] = any;
    }
  }
  int g = ib * 256 + tid;  // 0..4095
  int tt = g - 2048;
  uint64_t w = 0;
  for (int jj = 0; jj < 64; ++jj) {
    int d = tt - jj; d = d < 0 ? -d : d;
    if (d < 2048 && slut[d]) w |= (1ull << jj);
  }
  maskw[g] = w;
}

// ---------------- async global->LDS 16B -------------------------------------
__device__ __forceinline__ void cp16(half_t* lds, const half_t* g) {
  __builtin_amdgcn_global_load_lds(
      (const __attribute__((address_space(1))) uint32_t*)g,
      (__attribute__((address_space(3))) uint32_t*)lds, 16, 0, 0);
}

// ---------------- fused q+kv projection GEMM: 128x64 tiles ------------------
// grid (32, 48): by<16 -> q-proj (n0=by*64, scale folded), else kv-proj.
// 24KB LDS -> 6 blocks/CU. Epilogue via LDS round-trip, 16B stores.
__global__ __launch_bounds__(256) void gemm_qkv(
    const half_t* __restrict__ xq, const half_t* __restrict__ xkv,
    const half_t* __restrict__ wqT, const half_t* __restrict__ wkvT,
    const float* __restrict__ bq, const float* __restrict__ bkv,
    half_t* __restrict__ qout, half_t* __restrict__ kout,
    half_t* __restrict__ vTout) {
  extern __shared__ char smemraw[];
  half_t* As = (half_t*)smemraw;  // 2 x 128x32 halves (16KB)
  half_t* Bs = As + 8192;         // 2 x 64x32 halves (8KB)
  const int K = 1024;
  bool isq = blockIdx.y < 16;
  const half_t* A = isq ? xq : xkv;
  const half_t* Bt = isq ? wqT : wkvT;
  const float* bias = isq ? bq : bkv;
  int n0 = (isq ? blockIdx.y : (blockIdx.y - 16)) * 64;
  int m0 = blockIdx.x * 128;

  int tid = threadIdx.x;
  int wave = tid >> 6, lane = tid & 63;
  int c = lane & 15, quad = lane >> 4;
  int wm = (wave >> 1) * 64, wn = (wave & 1) * 32;

  floatx4 acc[4][2] = {};
  int arow = tid >> 2, akc = (tid & 3) * 8;

  cp16(&As[wave * 512], A + (size_t)(m0 + arow) * K + akc);
  cp16(&As[2048 + wave * 512], A + (size_t)(m0 + 64 + arow) * K + akc);
  cp16(&Bs[wave * 512], Bt + (size_t)(n0 + arow) * K + akc);

  for (int kt = 0; kt < 32; ++kt) {
    __syncthreads();
    if (kt + 1 < 32) {
      int k0 = (kt + 1) * 32;
      int b = (kt + 1) & 1;
      cp16(&As[b * 4096 + wave * 512], A + (size_t)(m0 + arow) * K + k0 + akc);
      cp16(&As[b * 4096 + 2048 + wave * 512], A + (size_t)(m0 + 64 + arow) * K + k0 + akc);
      cp16(&Bs[b * 2048 + wave * 512], Bt + (size_t)(n0 + arow) * K + k0 + akc);
    }
    int b = kt & 1;
    half8 af[4], bf[2];
#pragma unroll
    for (int mt = 0; mt < 4; ++mt)
      af[mt] = *(const half8*)&As[b * 4096 + (wm + mt * 16 + c) * 32 + quad * 8];
#pragma unroll
    for (int nt = 0; nt < 2; ++nt)
      bf[nt] = *(const half8*)&Bs[b * 2048 + (wn + nt * 16 + c) * 32 + quad * 8];
#pragma unroll
    for (int mt = 0; mt < 4; ++mt)
#pragma unroll
      for (int nt = 0; nt < 2; ++nt)
        acc[mt][nt] = MFMA32K(af[mt], bf[nt], acc[mt][nt]);
  }

  __syncthreads();  // all waves done reading staging LDS
  half_t* ep = (half_t*)smemraw;
  int bb = m0 >> 11, sbase = m0 & 2047;
  bool isv = (!isq) && (n0 >= 1024);
  int h = (n0 >> 6) & 15;

  if (!isv) {  // q or k: ep[m][n] stride 64 -> [bh][s][d]
#pragma unroll
    for (int nt = 0; nt < 2; ++nt) {
      int nl = wn + nt * 16 + c;
      float bv = bias[n0 + nl];
#pragma unroll
      for (int mt = 0; mt < 4; ++mt)
#pragma unroll
        for (int r = 0; r < 4; ++r) {
          int ml = wm + mt * 16 + quad * 4 + r;
          float v = acc[mt][nt][r] + bv;
          if (isq) v *= QSCALE;
          ep[ml * 64 + nl] = (half_t)v;
        }
    }
    __syncthreads();
    half_t* outp = isq ? qout : kout;
#pragma unroll
    for (int rd = 0; rd < 4; ++rd) {
      int id = rd * 256 + tid;  // 1024 chunks of 16B (128 rows x 8)
      int ml = id >> 3, ch = id & 7;
      half8 v = *(const half8*)&ep[ml * 64 + ch * 8];
      *(half8*)(outp + ((size_t)(bb * 16 + h) * SEQ + sbase + ml) * 64 + ch * 8) = v;
    }
  } else {  // v: ep[n][m] stride 136 -> [bh][d][s]
#pragma unroll
    for (int nt = 0; nt < 2; ++nt) {
      int nl = wn + nt * 16 + c;
      float bv = bias[n0 + nl];
#pragma unroll
      for (int mt = 0; mt < 4; ++mt) {
        int ml = wm + mt * 16 + quad * 4;
        half4 hv;
#pragma unroll
        for (int r = 0; r < 4; ++r) hv[r] = (half_t)(acc[mt][nt][r] + bv);
        *(half4*)&ep[nl * 136 + ml] = hv;
      }
    }
    __syncthreads();
#pragma unroll
    for (int rd = 0; rd < 4; ++rd) {
      int id = rd * 256 + tid;  // 1024 chunks (64 n-rows x 16)
      int nl = id >> 4, mc = id & 15;
      int d = (n0 + nl) & 63;
      half8 v = *(const half8*)&ep[nl * 136 + mc * 8];
      *(half8*)(vTout + ((size_t)(bb * 16 + h) * 64 + d) * SEQ + sbase + mc * 8) = v;
    }
  }
}

// ---------------- out-projection GEMM: 64x64 tiles, fp32 out ----------------
// grid (64, 16) = 1024 blocks = 4/CU; 16KB LDS.
__global__ __launch_bounds__(256) void gemm_out(
    const half_t* __restrict__ A, const half_t* __restrict__ Bt,
    const float* __restrict__ bias, float* __restrict__ outf) {
  __shared__ half_t As[2][64 * 32];
  __shared__ half_t Bs[2][64 * 32];
  const int K = 1024;
  int tid = threadIdx.x;
  int wave = tid >> 6, lane = tid & 63;
  int c = lane & 15, quad = lane >> 4;
  int wm = (wave >> 1) * 32, wn = (wave & 1) * 32;
  int m0 = blockIdx.x * 64, n0 = blockIdx.y * 64;

  floatx4 acc[2][2] = {};
  int arow = tid >> 2, akc = (tid & 3) * 8;

  cp16(&As[0][wave * 512], A + (size_t)(m0 + arow) * K + akc);
  cp16(&Bs[0][wave * 512], Bt + (size_t)(n0 + arow) * K + akc);

  for (int kt = 0; kt < 32; ++kt) {
    __syncthreads();
    if (kt + 1 < 32) {
      int k0 = (kt + 1) * 32;
      int b = (kt + 1) & 1;
      cp16(&As[b][wave * 512], A + (size_t)(m0 + arow) * K + k0 + akc);
      cp16(&Bs[b][wave * 512], Bt + (size_t)(n0 + arow) * K + k0 + akc);
    }
    int b = kt & 1;
    half8 af[2], bf[2];
#pragma unroll
    for (int mt = 0; mt < 2; ++mt)
      af[mt] = *(const half8*)&As[b][(wm + mt * 16 + c) * 32 + quad * 8];
#pragma unroll
    for (int nt = 0; nt < 2; ++nt)
      bf[nt] = *(const half8*)&Bs[b][(wn + nt * 16 + c) * 32 + quad * 8];
#pragma unroll
    for (int mt = 0; mt < 2; ++mt)
#pragma unroll
      for (int nt = 0; nt < 2; ++nt)
        acc[mt][nt] = MFMA32K(af[mt], bf[nt], acc[mt][nt]);
  }

#pragma unroll
  for (int nt = 0; nt < 2; ++nt) {
    int n = n0 + wn + nt * 16 + c;
    float bv = bias[n];
#pragma unroll
    for (int mt = 0; mt < 2; ++mt)
#pragma unroll
      for (int r = 0; r < 4; ++r) {
        int m = m0 + wm + mt * 16 + quad * 4 + r;
        outf[(size_t)m * 1024 + n] = acc[mt][nt][r] + bv;
      }
  }
}

// ---------------- masked flash attention ------------------------------------
// 512 blocks x 512 threads: 128 i-rows/block (8 waves x 16). XCD swizzle.
__global__ __launch_bounds__(512) void attn_kernel(
    const half_t* __restrict__ qb, const half_t* __restrict__ kb,
    const half_t* __restrict__ vTg, half_t* __restrict__ ctx,
    const uint64_t* __restrict__ maskw, const uint8_t* __restrict__ tok,
    const uint8_t* __restrict__ tok16g) {
  __shared__ half_t kT[64 * 64];
  __shared__ half_t vT[64 * 64];
  __shared__ half_t ot[128 * 72];
  __shared__ int list[34];
  __shared__ uint8_t tok16s[256];

  int tid = threadIdx.x, wave = tid >> 6, lane = tid & 63;
  int c = lane & 15, q = lane >> 4;
  int id = blockIdx.x;
  int bh = (id & 7) * 4 + ((id >> 3) & 3);  // XCD-major: bh fixed per XCD
  int it128 = id >> 5;
  int i0 = it128 << 7;
  const half_t* qbase = qb + (size_t)bh * SEQ * HD;
  const half_t* kg = kb + (size_t)bh * SEQ * HD;
  const half_t* vg = vTg + (size_t)bh * HD * SEQ;

  if (tid < 256) tok16s[tid] = tok16g[tid];
  if (wave == 0) {
    int jt = lane;
    int base = i0 >> 6;
    bool act = (jt < 32) &&
               (tok[(jt - base) + 32] | tok[(jt - base - 1) + 32]);
    unsigned long long bal = __ballot(act);
    if (act) {
      int pre = __popcll(bal & ((1ull << jt) - 1));
      list[1 + pre] = jt << 6;
    }
    if (lane == 0) list[0] = __popcll(bal);
  }

  int i_row = i0 + wave * 16 + c;
  int it16 = (i0 >> 4) + wave;
  half8 qf0 = *(const half8*)(qbase + (size_t)i_row * 64 + q * 8);
  half8 qf1 = *(const half8*)(qbase + (size_t)i_row * 64 + 32 + q * 8);

  floatx4 oacc[4] = {};
  floatx4 lacc = {};
  half4 ones;
  ones[0] = (half_t)1.f; ones[1] = (half_t)1.f;
  ones[2] = (half_t)1.f; ones[3] = (half_t)1.f;

  int srow = tid >> 3;      // 0..63
  int sch = tid & 7;        // 0..7
  int ssw = srow & 7;

  __syncthreads();  // list + tok16s ready
  int nact = list[0];
  int j0 = list[1];

  half8 kr = *(const half8*)(kg + (size_t)(j0 + srow) * 64 + sch * 8);
  half8 vr = *(const half8*)(vg + (size_t)srow * SEQ + j0 + sch * 8);

  for (int ti = 0; ti < nact; ++ti) {
    uint64_t w = maskw[(i_row - j0) + 2048];
    int bidx = (j0 >> 4) - it16 + 128;
    __syncthreads();
    *(half8*)&kT[srow * 64 + ((sch ^ ssw) * 8)] = kr;
    *(half8*)&vT[srow * 64 + ((sch ^ ssw) * 8)] = vr;
    int j0n = j0;
    if (ti + 1 < nact) {
      j0n = list[2 + ti];
      kr = *(const half8*)(kg + (size_t)(j0n + srow) * 64 + sch * 8);
      vr = *(const half8*)(vg + (size_t)srow * SEQ + j0n + sch * 8);
    }
    __syncthreads();

    uint32_t wlo = (uint32_t)(w >> (4 * q));
    uint32_t whi = (uint32_t)(w >> (32 + 4 * q));
#pragma unroll
    for (int jt = 0; jt < 4; ++jt) {
      if (!tok16s[bidx + jt]) continue;  // wave-uniform subtile skip
      int row = jt * 16 + c;
      int sw = c & 7;
      half8 a0 = *(const half8*)&kT[row * 64 + ((q ^ sw) * 8)];
      half8 a1 = *(const half8*)&kT[row * 64 + (((4 + q) ^ sw) * 8)];
      floatx4 t = {};
      t = MFMA32K(a0, qf0, t);
      t = MFMA32K(a1, qf1, t);
      uint32_t ww = (jt < 2) ? wlo : whi;
#pragma unroll
      for (int r = 0; r < 4; ++r) {
        float p = __builtin_exp2f(t[r]);
        int bitpos = 16 * (jt & 1) + r;
        uint32_t msk = (uint32_t)(((int)(ww << (31 - bitpos))) >> 31);
        t[r] = __uint_as_float(__float_as_uint(p) & msk);
      }
      auto lo = __builtin_amdgcn_cvt_pkrtz(t[0], t[1]);
      auto hi = __builtin_amdgcn_cvt_pkrtz(t[2], t[3]);
      half4 pb;
      pb[0] = lo[0]; pb[1] = lo[1]; pb[2] = hi[0]; pb[3] = hi[1];
      lacc = MFMA16(ones, pb, lacc);
#pragma unroll
      for (int mt = 0; mt < 4; ++mt) {
        int drow = mt * 16 + c;
        int ch = 2 * jt + (q >> 1);
        half4 a = *(const half4*)&vT[drow * 64 + ((ch ^ sw) * 8) + (q & 1) * 4];
        oacc[mt] = MFMA16(a, pb, oacc[mt]);
      }
    }
    j0 = j0n;
  }

  // epilogue: normalize, transpose via LDS, coalesced ctx write
  float inv_l = 1.0f / lacc[0];
#pragma unroll
  for (int mt = 0; mt < 4; ++mt)
#pragma unroll
    for (int r = 0; r < 4; ++r)
      ot[(wave * 16 + c) * 72 + mt * 16 + 4 * q + r] = (half_t)(oacc[mt][r] * inv_l);
  __syncthreads();
  {
    int row = tid >> 2, chq = tid & 3;  // 128 rows x 4 chunk-pairs
    int b = bh >> 4, h = bh & 15;
    size_t base = (((size_t)(b * SEQ + i0 + row) * NH) + h) * 64 + chq * 16;
    half8 v0 = *(const half8*)&ot[row * 72 + chq * 16];
    half8 v1 = *(const half8*)&ot[row * 72 + chq * 16 + 8];
    *(half8*)(ctx + base) = v0;
    *(half8*)(ctx + base + 8) = v1;
  }
}

// ---------------- launch -----------------------------------------------------
extern "C" void kernel_launch(void* const* d_in, const int* in_sizes, int n_in,
                              void* d_out, int out_size, void* d_ws, size_t ws_size,
                              hipStream_t stream) {
  const float* query = (const float*)d_in[0];
  const float* key_value = (const float*)d_in[1];
  const float* Wq = (const float*)d_in[2];
  const float* bq = (const float*)d_in[3];
  const float* Wkv = (const float*)d_in[4];
  const float* bkv = (const float*)d_in[5];
  const float* Wo = (const float*)d_in[6];
  const float* bo = (const float*)d_in[7];

  char* ws = (char*)d_ws;
  uint8_t* tok = (uint8_t*)ws;               // 64
  uint8_t* tok16 = (uint8_t*)(ws + 1024);    // 256
  uint64_t* maskw = (uint64_t*)(ws + 4096);  // 32KB
  const size_t MB = 1ull << 20;
  half_t* xq = (half_t*)(ws + 1 * MB);    // 8MB; reused as ctx after qkv gemm
  half_t* xkv = (half_t*)(ws + 9 * MB);   // 8MB
  half_t* wqT = (half_t*)(ws + 17 * MB);  // 2MB
  half_t* wkvT = (half_t*)(ws + 19 * MB); // 4MB
  half_t* woT = (half_t*)(ws + 23 * MB);  // 2MB
  half_t* qbuf = (half_t*)(ws + 25 * MB); // 8MB
  half_t* kbuf = (half_t*)(ws + 33 * MB); // 8MB
  half_t* vTg = (half_t*)(ws + 41 * MB);  // 8MB ([bh][d][s])
  half_t* ctx = xq;                       // alias (xq dead after proj)

  hipLaunchKernelGGL(prep, dim3(4112), dim3(256), 0, stream,
                     query, key_value, Wq, Wkv, Wo, xq, xkv, wqT, wkvT, woT,
                     tok, tok16, maskw);
  hipLaunchKernelGGL(gemm_qkv, dim3(32, 48), dim3(256), 24576, stream,
                     xq, xkv, wqT, wkvT, bq, bkv, qbuf, kbuf, vTg);
  hipLaunchKernelGGL(attn_kernel, dim3(512), dim3(512), 0, stream,
                     qbuf, kbuf, vTg, ctx, maskw, tok, tok16);
  hipLaunchKernelGGL(gemm_out, dim3(64, 16), dim3(256), 0, stream,
                     ctx, woT, bo, (float*)d_out);
}

// Round 9
// 216.520 us; speedup vs baseline: 1.0263x; 1.0263x over previous
//
#include <hip/hip_runtime.h>
#include <stdint.h>

typedef _Float16 half_t;
typedef __attribute__((ext_vector_type(8))) _Float16 half8;
typedef __attribute__((ext_vector_type(4))) _Float16 half4;
typedef __attribute__((ext_vector_type(4))) float floatx4;

#define SEQ 2048
#define NH 16
#define HD 64

#define MFMA16(a, b, c) __builtin_amdgcn_mfma_f32_16x16x16f16(a, b, c, 0, 0, 0)
#define MFMA32K(a, b, c) __builtin_amdgcn_mfma_f32_16x16x32_f16(a, b, c, 0, 0, 0)

// SCALE * log2(e): scores exit QK in log2 domain -> raw v_exp_f32
#define QSCALE 0.1803368801111306f

// ---------------- prep: casts + weight transposes + mask tables -------------
// grid 3088: 2048 cast (16KB each), 1024 transpose (64x64 f32 tiles,
// float4 reads + 128B-contiguous writes), 16 mask.
__global__ __launch_bounds__(256) void prep(
    const float* __restrict__ query, const float* __restrict__ key_value,
    const float* __restrict__ Wq, const float* __restrict__ Wkv,
    const float* __restrict__ Wo, half_t* __restrict__ xq,
    half_t* __restrict__ xkv, half_t* __restrict__ wqT,
    half_t* __restrict__ wkvT, half_t* __restrict__ woT,
    uint8_t* __restrict__ tok, uint8_t* __restrict__ tok16,
    uint64_t* __restrict__ maskw) {
  int bx = blockIdx.x, tid = threadIdx.x;
  if (bx < 2048) {  // fp32 -> f16 casts, 4096 elements per block
    const float* s; half_t* d; int base;
    if (bx < 1024) { s = query; d = xq; base = bx * 4096; }
    else { s = key_value; d = xkv; base = (bx - 1024) * 4096; }
#pragma unroll
    for (int u = 0; u < 4; ++u) {
      int i = base + u * 1024 + tid * 4;
      floatx4 v = *(const floatx4*)(s + i);
      half4 h;
      h[0] = (half_t)v[0]; h[1] = (half_t)v[1];
      h[2] = (half_t)v[2]; h[3] = (half_t)v[3];
      *(half4*)(d + i) = h;
    }
    return;
  }
  if (bx < 3072) {  // weight transpose+cast, 64x64 f32 tile per block
    __shared__ float tile[64][65];
    int id = bx - 2048;  // 0..1023
    const float* W; half_t* Wt; int N, nt, kt;
    if (id < 256) { W = Wq; Wt = wqT; N = 1024; nt = id & 15; kt = id >> 4; }
    else if (id < 768) { int i2 = id - 256; W = Wkv; Wt = wkvT; N = 2048; nt = i2 & 31; kt = i2 >> 5; }
    else { int i2 = id - 768; W = Wo; Wt = woT; N = 1024; nt = i2 & 15; kt = i2 >> 4; }
    const int K = 1024;
    int n0 = nt * 64, k0 = kt * 64;
    {
      int rr = tid >> 4, cc = (tid & 15) * 4;
#pragma unroll
      for (int u = 0; u < 4; ++u) {
        floatx4 v = *(const floatx4*)(W + (size_t)(k0 + rr + u * 16) * N + n0 + cc);
        tile[rr + u * 16][cc] = v[0];
        tile[rr + u * 16][cc + 1] = v[1];
        tile[rr + u * 16][cc + 2] = v[2];
        tile[rr + u * 16][cc + 3] = v[3];
      }
    }
    __syncthreads();
    {
      int n = tid >> 2, q4 = tid & 3;
      half_t h[16];
#pragma unroll
      for (int s = 0; s < 16; ++s) h[s] = (half_t)tile[q4 * 16 + s][n];
      half_t* dst = Wt + (size_t)(n0 + n) * K + k0 + q4 * 16;
      *(half8*)dst = *(half8*)&h[0];
      *(half8*)(dst + 8) = *(half8*)&h[8];
    }
    return;
  }
  // mask tables
  __shared__ uint8_t slut[2048];
  int ib = bx - 3072;
  for (int d = tid; d < 2048; d += 256) {
    int x = d;
    bool ok = true;
    for (int it = 0; it < 7; ++it) { ok &= ((x % 3) != 1); x /= 3; }
    ok &= (x == 0);
    slut[d] = (ok || d <= 64) ? 1 : 0;
  }
  __syncthreads();
  if (ib == 0) {
    if (tid < 64) {  // 64-gran tile activity
      int delta = tid - 32;
      int lo = delta * 64 - 63, hi = delta * 64 + 63;
      uint8_t any = 0;
      for (int x = lo; x <= hi; ++x) {
        int a = x < 0 ? -x : x;
        if (a < 2048) any |= slut[a];
      }
      tok[tid] = any;
    }
    {  // 16-gran subtile activity
      int d16 = tid - 128;
      int ctr = d16 * 16;
      uint8_t any = 0;
      for (int x = ctr - 15; x <= ctr + 15; ++x) {
        int a = x < 0 ? -x : x;
        if (a < 2048) any |= slut[a];
      }
      tok16[tid] = any;
    }
  }
  int g = ib * 256 + tid;  // 0..4095
  int tt = g - 2048;
  uint64_t w = 0;
  for (int jj = 0; jj < 64; ++jj) {
    int d = tt - jj; d = d < 0 ? -d : d;
    if (d < 2048 && slut[d]) w |= (1ull << jj);
  }
  maskw[g] = w;
}

// ---------------- async global->LDS 16B -------------------------------------
__device__ __forceinline__ void cp16(half_t* lds, const half_t* g) {
  __builtin_amdgcn_global_load_lds(
      (const __attribute__((address_space(1))) uint32_t*)g,
      (__attribute__((address_space(3))) uint32_t*)lds, 16, 0, 0);
}

// ---------------- fused q+kv projection GEMM (r7 config) --------------------
// grid (32, 24): by<8 -> q-proj (scale folded), else kv-proj. 34KB dyn LDS.
__global__ __launch_bounds__(256) void gemm_qkv(
    const half_t* __restrict__ xq, const half_t* __restrict__ xkv,
    const half_t* __restrict__ wqT, const half_t* __restrict__ wkvT,
    const float* __restrict__ bq, const float* __restrict__ bkv,
    half_t* __restrict__ qout, half_t* __restrict__ kout,
    half_t* __restrict__ vTout) {
  extern __shared__ char smemraw[];
  half_t* As = (half_t*)smemraw;  // 2 x 128x32
  half_t* Bs = As + 8192;         // 2 x 128x32
  const int K = 1024;
  bool isq = blockIdx.y < 8;
  const half_t* A = isq ? xq : xkv;
  const half_t* Bt = isq ? wqT : wkvT;
  const float* bias = isq ? bq : bkv;
  int n0 = (isq ? blockIdx.y : (blockIdx.y - 8)) * 128;
  int m0 = blockIdx.x * 128;

  int tid = threadIdx.x;
  int wave = tid >> 6, lane = tid & 63;
  int c = lane & 15, quad = lane >> 4;
  int wm = (wave >> 1) * 64, wn = (wave & 1) * 64;

  floatx4 acc[4][4] = {};
  int arow = tid >> 2, akc = (tid & 3) * 8;

  cp16(&As[wave * 512], A + (size_t)(m0 + arow) * K + akc);
  cp16(&As[2048 + wave * 512], A + (size_t)(m0 + 64 + arow) * K + akc);
  cp16(&Bs[wave * 512], Bt + (size_t)(n0 + arow) * K + akc);
  cp16(&Bs[2048 + wave * 512], Bt + (size_t)(n0 + 64 + arow) * K + akc);

  for (int kt = 0; kt < 32; ++kt) {
    __syncthreads();
    if (kt + 1 < 32) {
      int k0 = (kt + 1) * 32;
      int b = (kt + 1) & 1;
      cp16(&As[b * 4096 + wave * 512], A + (size_t)(m0 + arow) * K + k0 + akc);
      cp16(&As[b * 4096 + 2048 + wave * 512], A + (size_t)(m0 + 64 + arow) * K + k0 + akc);
      cp16(&Bs[b * 4096 + wave * 512], Bt + (size_t)(n0 + arow) * K + k0 + akc);
      cp16(&Bs[b * 4096 + 2048 + wave * 512], Bt + (size_t)(n0 + 64 + arow) * K + k0 + akc);
    }
    int b = kt & 1;
    half8 af[4], bf[4];
#pragma unroll
    for (int mt = 0; mt < 4; ++mt)
      af[mt] = *(const half8*)&As[b * 4096 + (wm + mt * 16 + c) * 32 + quad * 8];
#pragma unroll
    for (int nt = 0; nt < 4; ++nt)
      bf[nt] = *(const half8*)&Bs[b * 4096 + (wn + nt * 16 + c) * 32 + quad * 8];
#pragma unroll
    for (int mt = 0; mt < 4; ++mt)
#pragma unroll
      for (int nt = 0; nt < 4; ++nt)
        acc[mt][nt] = MFMA32K(af[mt], bf[nt], acc[mt][nt]);
  }

  __syncthreads();
  half_t* ep = (half_t*)smemraw;
  int bb = m0 >> 11, sbase = m0 & 2047;
  bool isv = (!isq) && (n0 >= 1024);

  if (!isv) {  // q or k: ep[m][n] stride 128 -> [bh][s][d]
#pragma unroll
    for (int nt = 0; nt < 4; ++nt) {
      int nl = wn + nt * 16 + c;
      float bv = bias[n0 + nl];
#pragma unroll
      for (int mt = 0; mt < 4; ++mt)
#pragma unroll
        for (int r = 0; r < 4; ++r) {
          int ml = wm + mt * 16 + quad * 4 + r;
          float v = acc[mt][nt][r] + bv;
          if (isq) v *= QSCALE;
          ep[ml * 128 + nl] = (half_t)v;
        }
    }
    __syncthreads();
    half_t* outp = isq ? qout : kout;
#pragma unroll
    for (int rd = 0; rd < 8; ++rd) {
      int id = rd * 256 + tid;  // 2048 chunks of 16B
      int ml = id >> 4, ch = id & 15;
      int ng = n0 + ch * 8;
      int h = ng >> 6, d0 = ng & 63;
      half8 v = *(const half8*)&ep[ml * 128 + ch * 8];
      *(half8*)(outp + ((size_t)(bb * 16 + h) * SEQ + sbase + ml) * 64 + d0) = v;
    }
  } else {  // v: ep[n][m] stride 136 -> [bh][d][s]
#pragma unroll
    for (int nt = 0; nt < 4; ++nt) {
      int nl = wn + nt * 16 + c;
      float bv = bias[n0 + nl];
#pragma unroll
      for (int mt = 0; mt < 4; ++mt) {
        int ml = wm + mt * 16 + quad * 4;
        half4 hv;
#pragma unroll
        for (int r = 0; r < 4; ++r) hv[r] = (half_t)(acc[mt][nt][r] + bv);
        *(half4*)&ep[nl * 136 + ml] = hv;
      }
    }
    __syncthreads();
#pragma unroll
    for (int rd = 0; rd < 8; ++rd) {
      int id = rd * 256 + tid;
      int nl = id >> 4, mc = id & 15;
      int ng = n0 + nl;
      int h = (ng >> 6) & 15, d = ng & 63;
      half8 v = *(const half8*)&ep[nl * 136 + mc * 8];
      *(half8*)(vTout + ((size_t)(bb * 16 + h) * 64 + d) * SEQ + sbase + mc * 8) = v;
    }
  }
}

// ---------------- out-projection GEMM: 128x64 tiles, fp32 out (r7) ----------
__global__ __launch_bounds__(256) void gemm_out(
    const half_t* __restrict__ A, const half_t* __restrict__ Bt,
    const float* __restrict__ bias, float* __restrict__ outf) {
  __shared__ half_t As[2][128 * 32];
  __shared__ half_t Bs[2][64 * 32];
  const int K = 1024;
  int tid = threadIdx.x;
  int wave = tid >> 6, lane = tid & 63;
  int c = lane & 15, quad = lane >> 4;
  int wm = (wave >> 1) * 64, wn = (wave & 1) * 32;
  int m0 = blockIdx.x * 128, n0 = blockIdx.y * 64;

  floatx4 acc[4][2] = {};
  int arow = tid >> 2, akc = (tid & 3) * 8;

  cp16(&As[0][wave * 512], A + (size_t)(m0 + arow) * K + akc);
  cp16(&As[0][2048 + wave * 512], A + (size_t)(m0 + 64 + arow) * K + akc);
  cp16(&Bs[0][wave * 512], Bt + (size_t)(n0 + arow) * K + akc);

  for (int kt = 0; kt < 32; ++kt) {
    __syncthreads();
    if (kt + 1 < 32) {
      int k0 = (kt + 1) * 32;
      int b = (kt + 1) & 1;
      cp16(&As[b][wave * 512], A + (size_t)(m0 + arow) * K + k0 + akc);
      cp16(&As[b][2048 + wave * 512], A + (size_t)(m0 + 64 + arow) * K + k0 + akc);
      cp16(&Bs[b][wave * 512], Bt + (size_t)(n0 + arow) * K + k0 + akc);
    }
    int b = kt & 1;
    half8 af[4], bf[2];
#pragma unroll
    for (int mt = 0; mt < 4; ++mt)
      af[mt] = *(const half8*)&As[b][(wm + mt * 16 + c) * 32 + quad * 8];
#pragma unroll
    for (int nt = 0; nt < 2; ++nt)
      bf[nt] = *(const half8*)&Bs[b][(wn + nt * 16 + c) * 32 + quad * 8];
#pragma unroll
    for (int mt = 0; mt < 4; ++mt)
#pragma unroll
      for (int nt = 0; nt < 2; ++nt)
        acc[mt][nt] = MFMA32K(af[mt], bf[nt], acc[mt][nt]);
  }

#pragma unroll
  for (int nt = 0; nt < 2; ++nt) {
    int n = n0 + wn + nt * 16 + c;
    float bv = bias[n];
#pragma unroll
    for (int mt = 0; mt < 4; ++mt)
#pragma unroll
      for (int r = 0; r < 4; ++r) {
        int m = m0 + wm + mt * 16 + quad * 4 + r;
        outf[(size_t)m * 1024 + n] = acc[mt][nt][r] + bv;
      }
  }
}

// ---------------- masked flash attention ------------------------------------
// 512 blocks x 512 threads, 128 i-rows/block, XCD swizzle, 16-gran skip,
// double-buffered kT/vT -> ONE barrier per tile-iteration.
__global__ __launch_bounds__(512) void attn_kernel(
    const half_t* __restrict__ qb, const half_t* __restrict__ kb,
    const half_t* __restrict__ vTg, half_t* __restrict__ ctx,
    const uint64_t* __restrict__ maskw, const uint8_t* __restrict__ tok,
    const uint8_t* __restrict__ tok16g) {
  __shared__ half_t kT[2][64 * 64];
  __shared__ half_t vT[2][64 * 64];
  __shared__ half_t ot[128 * 72];
  __shared__ int list[34];
  __shared__ uint8_t tok16s[256];

  int tid = threadIdx.x, wave = tid >> 6, lane = tid & 63;
  int c = lane & 15, q = lane >> 4;
  int id = blockIdx.x;
  int bh = (id & 7) * 4 + ((id >> 3) & 3);  // XCD-major: bh fixed per XCD
  int it128 = id >> 5;
  int i0 = it128 << 7;
  const half_t* qbase = qb + (size_t)bh * SEQ * HD;
  const half_t* kg = kb + (size_t)bh * SEQ * HD;
  const half_t* vg = vTg + (size_t)bh * HD * SEQ;

  if (tid < 256) tok16s[tid] = tok16g[tid];
  if (wave == 0) {
    int jt = lane;
    int base = i0 >> 6;
    bool act = (jt < 32) &&
               (tok[(jt - base) + 32] | tok[(jt - base - 1) + 32]);
    unsigned long long bal = __ballot(act);
    if (act) {
      int pre = __popcll(bal & ((1ull << jt) - 1));
      list[1 + pre] = jt << 6;
    }
    if (lane == 0) list[0] = __popcll(bal);
  }

  int i_row = i0 + wave * 16 + c;
  int it16 = (i0 >> 4) + wave;
  half8 qf0 = *(const half8*)(qbase + (size_t)i_row * 64 + q * 8);
  half8 qf1 = *(const half8*)(qbase + (size_t)i_row * 64 + 32 + q * 8);

  floatx4 oacc[4] = {};
  floatx4 lacc = {};
  half4 ones;
  ones[0] = (half_t)1.f; ones[1] = (half_t)1.f;
  ones[2] = (half_t)1.f; ones[3] = (half_t)1.f;

  int srow = tid >> 3;      // 0..63
  int sch = tid & 7;        // 0..7
  int ssw = srow & 7;
  int soff = srow * 64 + ((sch ^ ssw) * 8);

  __syncthreads();  // list + tok16s ready
  int nact = list[0];

  // prologue: tile0 -> buf0; tile1 -> regs
  {
    int j0 = list[1];
    *(half8*)&kT[0][soff] = *(const half8*)(kg + (size_t)(j0 + srow) * 64 + sch * 8);
    *(half8*)&vT[0][soff] = *(const half8*)(vg + (size_t)srow * SEQ + j0 + sch * 8);
  }
  half8 kr, vr;
  if (nact > 1) {
    int j1 = list[2];
    kr = *(const half8*)(kg + (size_t)(j1 + srow) * 64 + sch * 8);
    vr = *(const half8*)(vg + (size_t)srow * SEQ + j1 + sch * 8);
  }
  __syncthreads();  // buf0 ready
  int buf = 0;

  for (int ti = 0; ti < nact; ++ti) {
    int jcur = list[1 + ti];
    uint64_t w = maskw[(i_row - jcur) + 2048];
    int bidx = (jcur >> 4) - it16 + 128;
    if (ti + 1 < nact) {
      // write tile ti+1 into the other buffer (nobody reads it now)
      *(half8*)&kT[buf ^ 1][soff] = kr;
      *(half8*)&vT[buf ^ 1][soff] = vr;
      if (ti + 2 < nact) {
        int j2 = list[3 + ti];
        kr = *(const half8*)(kg + (size_t)(j2 + srow) * 64 + sch * 8);
        vr = *(const half8*)(vg + (size_t)srow * SEQ + j2 + sch * 8);
      }
    }
    const half_t* kTb = &kT[buf][0];
    const half_t* vTb = &vT[buf][0];

    uint32_t wlo = (uint32_t)(w >> (4 * q));
    uint32_t whi = (uint32_t)(w >> (32 + 4 * q));
#pragma unroll
    for (int jt = 0; jt < 4; ++jt) {
      if (!tok16s[bidx + jt]) continue;  // wave-uniform subtile skip
      int row = jt * 16 + c;
      int sw = c & 7;
      half8 a0 = *(const half8*)&kTb[row * 64 + ((q ^ sw) * 8)];
      half8 a1 = *(const half8*)&kTb[row * 64 + (((4 + q) ^ sw) * 8)];
      floatx4 t = {};
      t = MFMA32K(a0, qf0, t);
      t = MFMA32K(a1, qf1, t);
      uint32_t ww = (jt < 2) ? wlo : whi;
#pragma unroll
      for (int r = 0; r < 4; ++r) {
        float p = __builtin_exp2f(t[r]);
        int bitpos = 16 * (jt & 1) + r;
        uint32_t msk = (uint32_t)(((int)(ww << (31 - bitpos))) >> 31);
        t[r] = __uint_as_float(__float_as_uint(p) & msk);
      }
      auto lo = __builtin_amdgcn_cvt_pkrtz(t[0], t[1]);
      auto hi = __builtin_amdgcn_cvt_pkrtz(t[2], t[3]);
      half4 pb;
      pb[0] = lo[0]; pb[1] = lo[1]; pb[2] = hi[0]; pb[3] = hi[1];
      lacc = MFMA16(ones, pb, lacc);
#pragma unroll
      for (int mt = 0; mt < 4; ++mt) {
        int drow = mt * 16 + c;
        int ch = 2 * jt + (q >> 1);
        half4 a = *(const half4*)&vTb[drow * 64 + ((ch ^ sw) * 8) + (q & 1) * 4];
        oacc[mt] = MFMA16(a, pb, oacc[mt]);
      }
    }
    __syncthreads();  // reads of buf done; writes to buf^1 visible
    buf ^= 1;
  }

  // epilogue: normalize, transpose via LDS, coalesced ctx write
  float inv_l = 1.0f / lacc[0];
#pragma unroll
  for (int mt = 0; mt < 4; ++mt)
#pragma unroll
    for (int r = 0; r < 4; ++r)
      ot[(wave * 16 + c) * 72 + mt * 16 + 4 * q + r] = (half_t)(oacc[mt][r] * inv_l);
  __syncthreads();
  {
    int row = tid >> 2, chq = tid & 3;  // 128 rows x 4 chunk-pairs
    int b = bh >> 4, h = bh & 15;
    size_t base = (((size_t)(b * SEQ + i0 + row) * NH) + h) * 64 + chq * 16;
    half8 v0 = *(const half8*)&ot[row * 72 + chq * 16];
    half8 v1 = *(const half8*)&ot[row * 72 + chq * 16 + 8];
    *(half8*)(ctx + base) = v0;
    *(half8*)(ctx + base + 8) = v1;
  }
}

// ---------------- launch -----------------------------------------------------
extern "C" void kernel_launch(void* const* d_in, const int* in_sizes, int n_in,
                              void* d_out, int out_size, void* d_ws, size_t ws_size,
                              hipStream_t stream) {
  const float* query = (const float*)d_in[0];
  const float* key_value = (const float*)d_in[1];
  const float* Wq = (const float*)d_in[2];
  const float* bq = (const float*)d_in[3];
  const float* Wkv = (const float*)d_in[4];
  const float* bkv = (const float*)d_in[5];
  const float* Wo = (const float*)d_in[6];
  const float* bo = (const float*)d_in[7];

  char* ws = (char*)d_ws;
  uint8_t* tok = (uint8_t*)ws;               // 64
  uint8_t* tok16 = (uint8_t*)(ws + 1024);    // 256
  uint64_t* maskw = (uint64_t*)(ws + 4096);  // 32KB
  const size_t MB = 1ull << 20;
  half_t* xq = (half_t*)(ws + 1 * MB);    // 8MB; reused as ctx after qkv gemm
  half_t* xkv = (half_t*)(ws + 9 * MB);   // 8MB
  half_t* wqT = (half_t*)(ws + 17 * MB);  // 2MB
  half_t* wkvT = (half_t*)(ws + 19 * MB); // 4MB
  half_t* woT = (half_t*)(ws + 23 * MB);  // 2MB
  half_t* qbuf = (half_t*)(ws + 25 * MB); // 8MB
  half_t* kbuf = (half_t*)(ws + 33 * MB); // 8MB
  half_t* vTg = (half_t*)(ws + 41 * MB);  // 8MB ([bh][d][s])
  half_t* ctx = xq;                       // alias (xq dead after proj)

  hipLaunchKernelGGL(prep, dim3(3088), dim3(256), 0, stream,
                     query, key_value, Wq, Wkv, Wo, xq, xkv, wqT, wkvT, woT,
                     tok, tok16, maskw);
  hipLaunchKernelGGL(gemm_qkv, dim3(32, 24), dim3(256), 34816, stream,
                     xq, xkv, wqT, wkvT, bq, bkv, qbuf, kbuf, vTg);
  hipLaunchKernelGGL(attn_kernel, dim3(512), dim3(512), 0, stream,
                     qbuf, kbuf, vTg, ctx, maskw, tok, tok16);
  hipLaunchKernelGGL(gemm_out, dim3(32, 16), dim3(256), 0, stream,
                     ctx, woT, bo, (float*)d_out);
}

// Round 10
// 212.050 us; speedup vs baseline: 1.0480x; 1.0211x over previous
//
#include <hip/hip_runtime.h>
#include <stdint.h>

typedef _Float16 half_t;
typedef __attribute__((ext_vector_type(8))) _Float16 half8;
typedef __attribute__((ext_vector_type(4))) _Float16 half4;
typedef __attribute__((ext_vector_type(4))) float floatx4;

#define SEQ 2048
#define NH 16
#define HD 64

#define MFMA16(a, b, c) __builtin_amdgcn_mfma_f32_16x16x16f16(a, b, c, 0, 0, 0)
#define MFMA32K(a, b, c) __builtin_amdgcn_mfma_f32_16x16x32_f16(a, b, c, 0, 0, 0)

// SCALE * log2(e): scores exit QK in log2 domain -> raw v_exp_f32
#define QSCALE 0.1803368801111306f

// ---------------- prep: casts + weight transposes + mask tables -------------
// grid 3088: 2048 cast, 1024 transpose (64x64 f32 tiles), 16 mask.
// maskh[t+2048][r] = allowed(|t-r|) as f16 0/1 (multiplicative mask).
__global__ __launch_bounds__(256) void prep(
    const float* __restrict__ query, const float* __restrict__ key_value,
    const float* __restrict__ Wq, const float* __restrict__ Wkv,
    const float* __restrict__ Wo, half_t* __restrict__ xq,
    half_t* __restrict__ xkv, half_t* __restrict__ wqT,
    half_t* __restrict__ wkvT, half_t* __restrict__ woT,
    uint8_t* __restrict__ tok, uint8_t* __restrict__ tok16,
    half_t* __restrict__ maskh) {
  int bx = blockIdx.x, tid = threadIdx.x;
  if (bx < 2048) {  // fp32 -> f16 casts, 4096 elements per block
    const float* s; half_t* d; int base;
    if (bx < 1024) { s = query; d = xq; base = bx * 4096; }
    else { s = key_value; d = xkv; base = (bx - 1024) * 4096; }
#pragma unroll
    for (int u = 0; u < 4; ++u) {
      int i = base + u * 1024 + tid * 4;
      floatx4 v = *(const floatx4*)(s + i);
      half4 h;
      h[0] = (half_t)v[0]; h[1] = (half_t)v[1];
      h[2] = (half_t)v[2]; h[3] = (half_t)v[3];
      *(half4*)(d + i) = h;
    }
    return;
  }
  if (bx < 3072) {  // weight transpose+cast, 64x64 f32 tile per block
    __shared__ float tile[64][65];
    int id = bx - 2048;  // 0..1023
    const float* W; half_t* Wt; int N, nt, kt;
    if (id < 256) { W = Wq; Wt = wqT; N = 1024; nt = id & 15; kt = id >> 4; }
    else if (id < 768) { int i2 = id - 256; W = Wkv; Wt = wkvT; N = 2048; nt = i2 & 31; kt = i2 >> 5; }
    else { int i2 = id - 768; W = Wo; Wt = woT; N = 1024; nt = i2 & 15; kt = i2 >> 4; }
    const int K = 1024;
    int n0 = nt * 64, k0 = kt * 64;
    {
      int rr = tid >> 4, cc = (tid & 15) * 4;
#pragma unroll
      for (int u = 0; u < 4; ++u) {
        floatx4 v = *(const floatx4*)(W + (size_t)(k0 + rr + u * 16) * N + n0 + cc);
        tile[rr + u * 16][cc] = v[0];
        tile[rr + u * 16][cc + 1] = v[1];
        tile[rr + u * 16][cc + 2] = v[2];
        tile[rr + u * 16][cc + 3] = v[3];
      }
    }
    __syncthreads();
    {
      int n = tid >> 2, q4 = tid & 3;
      half_t h[16];
#pragma unroll
      for (int s = 0; s < 16; ++s) h[s] = (half_t)tile[q4 * 16 + s][n];
      half_t* dst = Wt + (size_t)(n0 + n) * K + k0 + q4 * 16;
      *(half8*)dst = *(half8*)&h[0];
      *(half8*)(dst + 8) = *(half8*)&h[8];
    }
    return;
  }
  // mask tables
  __shared__ uint8_t slut[2048];
  int ib = bx - 3072;
  for (int d = tid; d < 2048; d += 256) {
    int x = d;
    bool ok = true;
    for (int it = 0; it < 7; ++it) { ok &= ((x % 3) != 1); x /= 3; }
    ok &= (x == 0);
    slut[d] = (ok || d <= 64) ? 1 : 0;
  }
  __syncthreads();
  if (ib == 0) {
    if (tid < 64) {  // 64-gran tile activity
      int delta = tid - 32;
      int lo = delta * 64 - 63, hi = delta * 64 + 63;
      uint8_t any = 0;
      for (int x = lo; x <= hi; ++x) {
        int a = x < 0 ? -x : x;
        if (a < 2048) any |= slut[a];
      }
      tok[tid] = any;
    }
    {  // 16-gran subtile activity
      int d16 = tid - 128;
      int ctr = d16 * 16;
      uint8_t any = 0;
      for (int x = ctr - 15; x <= ctr + 15; ++x) {
        int a = x < 0 ? -x : x;
        if (a < 2048) any |= slut[a];
      }
      tok16[tid] = any;
    }
  }
  {
    int g = ib * 256 + tid;  // 0..4095
    int t = g - 2048;
    half4 mh;
#pragma unroll
    for (int r = 0; r < 4; ++r) {
      int d = t - r; d = d < 0 ? -d : d;
      mh[r] = (half_t)((d < 2048 && slut[d]) ? 1.f : 0.f);
    }
    *(half4*)(maskh + (size_t)g * 4) = mh;
  }
}

// ---------------- async global->LDS 16B -------------------------------------
__device__ __forceinline__ void cp16(half_t* lds, const half_t* g) {
  __builtin_amdgcn_global_load_lds(
      (const __attribute__((address_space(1))) uint32_t*)g,
      (__attribute__((address_space(3))) uint32_t*)lds, 16, 0, 0);
}

// ---------------- fused q+kv projection GEMM (r7 config) --------------------
__global__ __launch_bounds__(256) void gemm_qkv(
    const half_t* __restrict__ xq, const half_t* __restrict__ xkv,
    const half_t* __restrict__ wqT, const half_t* __restrict__ wkvT,
    const float* __restrict__ bq, const float* __restrict__ bkv,
    half_t* __restrict__ qout, half_t* __restrict__ kout,
    half_t* __restrict__ vTout) {
  extern __shared__ char smemraw[];
  half_t* As = (half_t*)smemraw;  // 2 x 128x32
  half_t* Bs = As + 8192;         // 2 x 128x32
  const int K = 1024;
  bool isq = blockIdx.y < 8;
  const half_t* A = isq ? xq : xkv;
  const half_t* Bt = isq ? wqT : wkvT;
  const float* bias = isq ? bq : bkv;
  int n0 = (isq ? blockIdx.y : (blockIdx.y - 8)) * 128;
  int m0 = blockIdx.x * 128;

  int tid = threadIdx.x;
  int wave = tid >> 6, lane = tid & 63;
  int c = lane & 15, quad = lane >> 4;
  int wm = (wave >> 1) * 64, wn = (wave & 1) * 64;

  floatx4 acc[4][4] = {};
  int arow = tid >> 2, akc = (tid & 3) * 8;

  cp16(&As[wave * 512], A + (size_t)(m0 + arow) * K + akc);
  cp16(&As[2048 + wave * 512], A + (size_t)(m0 + 64 + arow) * K + akc);
  cp16(&Bs[wave * 512], Bt + (size_t)(n0 + arow) * K + akc);
  cp16(&Bs[2048 + wave * 512], Bt + (size_t)(n0 + 64 + arow) * K + akc);

  for (int kt = 0; kt < 32; ++kt) {
    __syncthreads();
    if (kt + 1 < 32) {
      int k0 = (kt + 1) * 32;
      int b = (kt + 1) & 1;
      cp16(&As[b * 4096 + wave * 512], A + (size_t)(m0 + arow) * K + k0 + akc);
      cp16(&As[b * 4096 + 2048 + wave * 512], A + (size_t)(m0 + 64 + arow) * K + k0 + akc);
      cp16(&Bs[b * 4096 + wave * 512], Bt + (size_t)(n0 + arow) * K + k0 + akc);
      cp16(&Bs[b * 4096 + 2048 + wave * 512], Bt + (size_t)(n0 + 64 + arow) * K + k0 + akc);
    }
    int b = kt & 1;
    half8 af[4], bf[4];
#pragma unroll
    for (int mt = 0; mt < 4; ++mt)
      af[mt] = *(const half8*)&As[b * 4096 + (wm + mt * 16 + c) * 32 + quad * 8];
#pragma unroll
    for (int nt = 0; nt < 4; ++nt)
      bf[nt] = *(const half8*)&Bs[b * 4096 + (wn + nt * 16 + c) * 32 + quad * 8];
#pragma unroll
    for (int mt = 0; mt < 4; ++mt)
#pragma unroll
      for (int nt = 0; nt < 4; ++nt)
        acc[mt][nt] = MFMA32K(af[mt], bf[nt], acc[mt][nt]);
  }

  __syncthreads();
  half_t* ep = (half_t*)smemraw;
  int bb = m0 >> 11, sbase = m0 & 2047;
  bool isv = (!isq) && (n0 >= 1024);

  if (!isv) {  // q or k: ep[m][n] stride 128 -> [bh][s][d]
#pragma unroll
    for (int nt = 0; nt < 4; ++nt) {
      int nl = wn + nt * 16 + c;
      float bv = bias[n0 + nl];
#pragma unroll
      for (int mt = 0; mt < 4; ++mt)
#pragma unroll
        for (int r = 0; r < 4; ++r) {
          int ml = wm + mt * 16 + quad * 4 + r;
          float v = acc[mt][nt][r] + bv;
          if (isq) v *= QSCALE;
          ep[ml * 128 + nl] = (half_t)v;
        }
    }
    __syncthreads();
    half_t* outp = isq ? qout : kout;
#pragma unroll
    for (int rd = 0; rd < 8; ++rd) {
      int id = rd * 256 + tid;  // 2048 chunks of 16B
      int ml = id >> 4, ch = id & 15;
      int ng = n0 + ch * 8;
      int h = ng >> 6, d0 = ng & 63;
      half8 v = *(const half8*)&ep[ml * 128 + ch * 8];
      *(half8*)(outp + ((size_t)(bb * 16 + h) * SEQ + sbase + ml) * 64 + d0) = v;
    }
  } else {  // v: ep[n][m] stride 136 -> [bh][d][s]
#pragma unroll
    for (int nt = 0; nt < 4; ++nt) {
      int nl = wn + nt * 16 + c;
      float bv = bias[n0 + nl];
#pragma unroll
      for (int mt = 0; mt < 4; ++mt) {
        int ml = wm + mt * 16 + quad * 4;
        half4 hv;
#pragma unroll
        for (int r = 0; r < 4; ++r) hv[r] = (half_t)(acc[mt][nt][r] + bv);
        *(half4*)&ep[nl * 136 + ml] = hv;
      }
    }
    __syncthreads();
#pragma unroll
    for (int rd = 0; rd < 8; ++rd) {
      int id = rd * 256 + tid;
      int nl = id >> 4, mc = id & 15;
      int ng = n0 + nl;
      int h = (ng >> 6) & 15, d = ng & 63;
      half8 v = *(const half8*)&ep[nl * 136 + mc * 8];
      *(half8*)(vTout + ((size_t)(bb * 16 + h) * 64 + d) * SEQ + sbase + mc * 8) = v;
    }
  }
}

// ---------------- out-projection GEMM: 128x64 tiles, coalesced fp32 out -----
__global__ __launch_bounds__(256) void gemm_out(
    const half_t* __restrict__ A, const half_t* __restrict__ Bt,
    const float* __restrict__ bias, float* __restrict__ outf) {
  extern __shared__ char smemraw[];
  half_t* As = (half_t*)smemraw;  // 2 x 128x32 (16KB)
  half_t* Bs = As + 8192;         // 2 x 64x32 (8KB)
  const int K = 1024;
  int tid = threadIdx.x;
  int wave = tid >> 6, lane = tid & 63;
  int c = lane & 15, quad = lane >> 4;
  int wm = (wave >> 1) * 64, wn = (wave & 1) * 32;
  int m0 = blockIdx.x * 128, n0 = blockIdx.y * 64;

  floatx4 acc[4][2] = {};
  int arow = tid >> 2, akc = (tid & 3) * 8;

  cp16(&As[wave * 512], A + (size_t)(m0 + arow) * K + akc);
  cp16(&As[2048 + wave * 512], A + (size_t)(m0 + 64 + arow) * K + akc);
  cp16(&Bs[wave * 512], Bt + (size_t)(n0 + arow) * K + akc);

  for (int kt = 0; kt < 32; ++kt) {
    __syncthreads();
    if (kt + 1 < 32) {
      int k0 = (kt + 1) * 32;
      int b = (kt + 1) & 1;
      cp16(&As[b * 4096 + wave * 512], A + (size_t)(m0 + arow) * K + k0 + akc);
      cp16(&As[b * 4096 + 2048 + wave * 512], A + (size_t)(m0 + 64 + arow) * K + k0 + akc);
      cp16(&Bs[b * 2048 + wave * 512], Bt + (size_t)(n0 + arow) * K + k0 + akc);
    }
    int b = kt & 1;
    half8 af[4], bf[2];
#pragma unroll
    for (int mt = 0; mt < 4; ++mt)
      af[mt] = *(const half8*)&As[b * 4096 + (wm + mt * 16 + c) * 32 + quad * 8];
#pragma unroll
    for (int nt = 0; nt < 2; ++nt)
      bf[nt] = *(const half8*)&Bs[b * 2048 + (wn + nt * 16 + c) * 32 + quad * 8];
#pragma unroll
    for (int mt = 0; mt < 4; ++mt)
#pragma unroll
      for (int nt = 0; nt < 2; ++nt)
        acc[mt][nt] = MFMA32K(af[mt], bf[nt], acc[mt][nt]);
  }

  // epilogue: LDS round-trip -> float4 coalesced stores
  __syncthreads();
  float* ep = (float*)smemraw;  // 128 x 64 fp32 = 32KB
#pragma unroll
  for (int nt = 0; nt < 2; ++nt) {
    int nl = wn + nt * 16 + c;
    float bv = bias[n0 + nl];
#pragma unroll
    for (int mt = 0; mt < 4; ++mt)
#pragma unroll
      for (int r = 0; r < 4; ++r) {
        int ml = wm + mt * 16 + quad * 4 + r;
        ep[ml * 64 + nl] = acc[mt][nt][r] + bv;
      }
  }
  __syncthreads();
#pragma unroll
  for (int rd = 0; rd < 8; ++rd) {
    int id = rd * 256 + tid;  // 2048 float4 chunks (128 rows x 16)
    int ml = id >> 4, ch = id & 15;
    floatx4 v = *(const floatx4*)&ep[ml * 64 + ch * 4];
    *(floatx4*)(outf + (size_t)(m0 + ml) * 1024 + n0 + ch * 4) = v;
  }
}

// ---------------- masked flash attention ------------------------------------
// 512 blocks x 512 threads, 128 i-rows/block, XCD swizzle, 16-gran skip,
// double-buffered kT/vT (one barrier/iter), multiplicative f16 mask,
// epilogue buffer aliased onto staging LDS (33KB total -> 4 blocks/CU).
__global__ __launch_bounds__(512) void attn_kernel(
    const half_t* __restrict__ qb, const half_t* __restrict__ kb,
    const half_t* __restrict__ vTg, half_t* __restrict__ ctx,
    const half_t* __restrict__ maskhg, const uint8_t* __restrict__ tok,
    const uint8_t* __restrict__ tok16g) {
  __shared__ half_t sm[16384];  // kT[2] @ 0, vT[2] @ 8192; ot aliases @ 0
  __shared__ int list[34];
  __shared__ uint8_t tok16s[256];

  int tid = threadIdx.x, wave = tid >> 6, lane = tid & 63;
  int c = lane & 15, q = lane >> 4;
  int id = blockIdx.x;
  int bh = (id & 7) * 4 + ((id >> 3) & 3);  // XCD-major: bh fixed per XCD
  int it128 = id >> 5;
  int i0 = it128 << 7;
  const half_t* qbase = qb + (size_t)bh * SEQ * HD;
  const half_t* kg = kb + (size_t)bh * SEQ * HD;
  const half_t* vg = vTg + (size_t)bh * HD * SEQ;

  if (tid < 256) tok16s[tid] = tok16g[tid];
  if (wave == 0) {
    int jt = lane;
    int base = i0 >> 6;
    bool act = (jt < 32) &&
               (tok[(jt - base) + 32] | tok[(jt - base - 1) + 32]);
    unsigned long long bal = __ballot(act);
    if (act) {
      int pre = __popcll(bal & ((1ull << jt) - 1));
      list[1 + pre] = jt << 6;
    }
    if (lane == 0) list[0] = __popcll(bal);
  }

  int i_row = i0 + wave * 16 + c;
  int it16 = (i0 >> 4) + wave;
  half8 qf0 = *(const half8*)(qbase + (size_t)i_row * 64 + q * 8);
  half8 qf1 = *(const half8*)(qbase + (size_t)i_row * 64 + 32 + q * 8);

  floatx4 oacc[4] = {};
  floatx4 lacc = {};
  half4 ones;
  ones[0] = (half_t)1.f; ones[1] = (half_t)1.f;
  ones[2] = (half_t)1.f; ones[3] = (half_t)1.f;

  int srow = tid >> 3;      // 0..63
  int sch = tid & 7;        // 0..7
  int ssw = srow & 7;
  int soff = srow * 64 + ((sch ^ ssw) * 8);

  __syncthreads();  // list + tok16s ready
  int nact = list[0];

  // prologue: tile0 -> buf0; tile1 -> regs
  {
    int j0 = list[1];
    *(half8*)&sm[soff] = *(const half8*)(kg + (size_t)(j0 + srow) * 64 + sch * 8);
    *(half8*)&sm[8192 + soff] = *(const half8*)(vg + (size_t)srow * SEQ + j0 + sch * 8);
  }
  half8 kr, vr;
  if (nact > 1) {
    int j1 = list[2];
    kr = *(const half8*)(kg + (size_t)(j1 + srow) * 64 + sch * 8);
    vr = *(const half8*)(vg + (size_t)srow * SEQ + j1 + sch * 8);
  }
  __syncthreads();  // buf0 ready
  int buf = 0;

  for (int ti = 0; ti < nact; ++ti) {
    int jcur = list[1 + ti];
    int bidx = (jcur >> 4) - it16 + 128;
    int tmbase = i_row - jcur - 4 * q + 2048;  // mask row index (minus jt*16)
    if (ti + 1 < nact) {
      *(half8*)&sm[(buf ^ 1) * 4096 + soff] = kr;
      *(half8*)&sm[8192 + (buf ^ 1) * 4096 + soff] = vr;
      if (ti + 2 < nact) {
        int j2 = list[3 + ti];
        kr = *(const half8*)(kg + (size_t)(j2 + srow) * 64 + sch * 8);
        vr = *(const half8*)(vg + (size_t)srow * SEQ + j2 + sch * 8);
      }
    }
    const half_t* kTb = &sm[buf * 4096];
    const half_t* vTb = &sm[8192 + buf * 4096];

#pragma unroll
    for (int jt = 0; jt < 4; ++jt) {
      if (!tok16s[bidx + jt]) continue;  // wave-uniform subtile skip
      int row = jt * 16 + c;
      int sw = c & 7;
      half8 a0 = *(const half8*)&kTb[row * 64 + ((q ^ sw) * 8)];
      half8 a1 = *(const half8*)&kTb[row * 64 + (((4 + q) ^ sw) * 8)];
      floatx4 t = {};
      t = MFMA32K(a0, qf0, t);
      t = MFMA32K(a1, qf1, t);
      // p = exp2(s) (f16-safe: |s| bounded), multiplicative f16 mask
      half4 mh = *(const half4*)(maskhg + (size_t)(tmbase - jt * 16) * 4);
      auto lo = __builtin_amdgcn_cvt_pkrtz(__builtin_exp2f(t[0]),
                                           __builtin_exp2f(t[1]));
      auto hi = __builtin_amdgcn_cvt_pkrtz(__builtin_exp2f(t[2]),
                                           __builtin_exp2f(t[3]));
      half4 pb;
      pb[0] = lo[0]; pb[1] = lo[1]; pb[2] = hi[0]; pb[3] = hi[1];
      pb *= mh;  // v_pk_mul_f16 x2: zero masked positions
      lacc = MFMA16(ones, pb, lacc);
#pragma unroll
      for (int mt = 0; mt < 4; ++mt) {
        int drow = mt * 16 + c;
        int ch = 2 * jt + (q >> 1);
        half4 a = *(const half4*)&vTb[drow * 64 + ((ch ^ sw) * 8) + (q & 1) * 4];
        oacc[mt] = MFMA16(a, pb, oacc[mt]);
      }
    }
    __syncthreads();  // reads of buf done; writes to buf^1 visible
    buf ^= 1;
  }

  // epilogue: normalize, transpose via LDS (aliased over staging), store
  half_t* ot = &sm[0];  // 128*72 = 9216 halves <= 16384
  float inv_l = 1.0f / lacc[0];
#pragma unroll
  for (int mt = 0; mt < 4; ++mt)
#pragma unroll
    for (int r = 0; r < 4; ++r)
      ot[(wave * 16 + c) * 72 + mt * 16 + 4 * q + r] = (half_t)(oacc[mt][r] * inv_l);
  __syncthreads();
  {
    int row = tid >> 2, chq = tid & 3;  // 128 rows x 4 chunk-pairs
    int b = bh >> 4, h = bh & 15;
    size_t base = (((size_t)(b * SEQ + i0 + row) * NH) + h) * 64 + chq * 16;
    half8 v0 = *(const half8*)&ot[row * 72 + chq * 16];
    half8 v1 = *(const half8*)&ot[row * 72 + chq * 16 + 8];
    *(half8*)(ctx + base) = v0;
    *(half8*)(ctx + base + 8) = v1;
  }
}

// ---------------- launch -----------------------------------------------------
extern "C" void kernel_launch(void* const* d_in, const int* in_sizes, int n_in,
                              void* d_out, int out_size, void* d_ws, size_t ws_size,
                              hipStream_t stream) {
  const float* query = (const float*)d_in[0];
  const float* key_value = (const float*)d_in[1];
  const float* Wq = (const float*)d_in[2];
  const float* bq = (const float*)d_in[3];
  const float* Wkv = (const float*)d_in[4];
  const float* bkv = (const float*)d_in[5];
  const float* Wo = (const float*)d_in[6];
  const float* bo = (const float*)d_in[7];

  char* ws = (char*)d_ws;
  uint8_t* tok = (uint8_t*)ws;               // 64
  uint8_t* tok16 = (uint8_t*)(ws + 1024);    // 256
  half_t* maskh = (half_t*)(ws + 4096);      // 32KB (4096 x half4)
  const size_t MB = 1ull << 20;
  half_t* xq = (half_t*)(ws + 1 * MB);    // 8MB; reused as ctx after qkv gemm
  half_t* xkv = (half_t*)(ws + 9 * MB);   // 8MB
  half_t* wqT = (half_t*)(ws + 17 * MB);  // 2MB
  half_t* wkvT = (half_t*)(ws + 19 * MB); // 4MB
  half_t* woT = (half_t*)(ws + 23 * MB);  // 2MB
  half_t* qbuf = (half_t*)(ws + 25 * MB); // 8MB
  half_t* kbuf = (half_t*)(ws + 33 * MB); // 8MB
  half_t* vTg = (half_t*)(ws + 41 * MB);  // 8MB ([bh][d][s])
  half_t* ctx = xq;                       // alias (xq dead after proj)

  hipLaunchKernelGGL(prep, dim3(3088), dim3(256), 0, stream,
                     query, key_value, Wq, Wkv, Wo, xq, xkv, wqT, wkvT, woT,
                     tok, tok16, maskh);
  hipLaunchKernelGGL(gemm_qkv, dim3(32, 24), dim3(256), 34816, stream,
                     xq, xkv, wqT, wkvT, bq, bkv, qbuf, kbuf, vTg);
  hipLaunchKernelGGL(attn_kernel, dim3(512), dim3(512), 0, stream,
                     qbuf, kbuf, vTg, ctx, maskh, tok, tok16);
  hipLaunchKernelGGL(gemm_out, dim3(32, 16), dim3(256), 32768, stream,
                     ctx, woT, bo, (float*)d_out);
}